// Round 6
// baseline (760.466 us; speedup 1.0000x reference)
//
#include <hip/hip_runtime.h>

// Problem constants (fixed by the reference)
#define D        64
#define V        1024
#define HQ       4
#define M_TOTAL  131072      // 32 * 4096 rows
#define MR       256         // rows per block (4 waves x 64 rows/wave)
#define NT       256         // threads per block
#define TAU_PK   2.5e-2f     // rescue threshold in packed s'+64 space:
                             // 2*bucket(7.8e-3) + split-err + margin (R3/R4-verified)
#define LOSS_SCALE (1.25f / 8388608.0f)
#define RT_STRIDE 68         // 64 + 4 pad (keeps rows 16B-aligned)

typedef __attribute__((ext_vector_type(8))) short short8;
typedef __attribute__((ext_vector_type(4))) float f32x4;

// ---- ordered-float <-> uint transform (for rescue argmin packing only) ----
__device__ __forceinline__ unsigned int f2ord(float f) {
  unsigned int b = __float_as_uint(f);
  return b ^ (((unsigned int)((int)b >> 31)) | 0x80000000u);
}
// bf16 round-to-nearest-even
__device__ __forceinline__ unsigned short f2bf(float f) {
  unsigned int u = __float_as_uint(f);
  return (unsigned short)((u + 0x7fffu + ((u >> 16) & 1u)) >> 16);
}

// ---- prep: codebook -> bf16 hi/lo MFMA fragments; W2 = 64 - 0.5*|w|^2; zero loss ----
// Fragment layout (short8 units within a stage): unit = ((ct*2+kk)*2+hl)*64 + lane,
// holding W[code=ct*16+(lane&15)][k=kk*32+(lane>>4)*8 + j], j=0..7 as bf16.
// C1-chain init = 64 - 0.5*w2 so s' = dot - 0.5*w2 + 64 > 0: argmin d2 == argmax s',
// positive => plain fmax ordering == uint ordering for the mantissa-packed index.
__global__ void vq_prep(const float* __restrict__ emb, unsigned short* __restrict__ Wfrag,
                        float* __restrict__ W2, float* __restrict__ out) {
  int t = blockIdx.x * NT + threadIdx.x;   // over HQ*V = 4096
  if (t == 0) out[0] = 0.0f;
  if (t >= HQ * V) return;
  int s = t >> 10, v = t & (V - 1);
  int ct = v >> 4, cl = v & 15;
  const float* e = emb + (size_t)t * D;
  float w2 = 0.0f;
  for (int k = 0; k < D; ++k) {
    float f = e[k];
    w2 += f * f;
    unsigned short hb = f2bf(f);
    float fh = __uint_as_float((unsigned int)hb << 16);
    unsigned short lb = f2bf(f - fh);
    int kk = k >> 5, q = (k >> 3) & 3, j = k & 7;
    size_t base = (((size_t)(s * 64 + ct) * 2 + kk) * 2) * 512
                + (size_t)(q * 16 + cl) * 8 + j;
    Wfrag[base]       = hb;   // hl = 0
    Wfrag[base + 512] = lb;   // hl = 1
  }
  W2[t] = 64.0f - 0.5f * w2;
}

// ---- main kernel: 256 rows/block, 4 waves x 64 rows, MFMA bf16-split, B from L2 ----
// R6: occupancy routes are exhausted (R1/R3: VGPR caps spill the ct-loop; R5: 8-wave
// block reaches 2 waves/SIMD but 128-reg squeeze + block-wide serialization nets
// -18%). At 1 wave/SIMD the ct-tile wall (~2100 cyc vs 386 cyc MFMA-pipe floor) is
// dependency latency. Chain-depth evidence: 2||4 chains = 483 us (R0), one 6-deep =
// 668 us (R4). R6 keeps R4's verified frame (220 VGPR, no spill, packed-index
// consume) and splits into THREE parallel 2-deep chains: C1=Ah*Bh (+w2 init),
// C2=Al*Bh, C3=Ah*Bl -> critical path 4->2 MFMA latencies, 12 independent chains
// in flight per ct across 4 rt's.
__launch_bounds__(NT, 1)
__global__ void vq_main(const float* __restrict__ latent,
                        const float* __restrict__ emb,
                        const unsigned short* __restrict__ Wfrag,
                        const float* __restrict__ W2,
                        float* __restrict__ out) {
  __shared__ float Rt[MR][RT_STRIDE];   // 69.6 KB fp32 residual
  __shared__ int idx_lds[MR];
  __shared__ int n_rescue;
  __shared__ int rescue_rows[MR];
  __shared__ unsigned long long resc_pack[4];   // per-wave rescue winners
  __shared__ float loss_red[NT];

  const int t    = threadIdx.x;
  const int lane = t & 63;
  const int w    = t >> 6;       // wave id: rows [w*64, w*64+64)
  const int cl   = lane & 15;
  const int q    = lane >> 4;
  const size_t row0 = (size_t)blockIdx.x * MR;

  if (t == 0) n_rescue = 0;

  // ---- load latent tile -> Rt (coalesced float4) ----
  {
    const float4* lg = (const float4*)(latent + row0 * D);
    #pragma unroll
    for (int k = 0; k < 16; ++k) {
      int i4 = t + k * NT;                 // 0..4095 float4s
      int row = i4 >> 4, dd = (i4 & 15) * 4;
      *(float4*)&Rt[row][dd] = lg[i4];
    }
  }

  float loss_acc = 0.0f;

  for (int stage = 0; stage < HQ; ++stage) {
    __syncthreads();           // Rt ready (initial load or previous stage's update)

    // ---- build A fragments (bf16 hi/lo) from Rt ----
    short8 Ah[4][2], Al[4][2];
    #pragma unroll
    for (int rt = 0; rt < 4; ++rt)
      #pragma unroll
      for (int kk = 0; kk < 2; ++kk) {
        const float* rp = &Rt[w * 64 + rt * 16 + cl][kk * 32 + q * 8];
        short8 h, l;
        #pragma unroll
        for (int j = 0; j < 8; ++j) {
          float f = rp[j];
          unsigned short hb = f2bf(f);
          float fh = __uint_as_float((unsigned int)hb << 16);
          h[j] = (short)hb;
          l[j] = (short)f2bf(f - fh);
        }
        Ah[rt][kk] = h; Al[rt][kk] = l;
      }

    // per-lane top-2 of packed M = (s'+64 with low-10 mantissa = 1023-code).
    // slot (rt,r) covers row = w*64+rt*16+q*4+r, cols ≡ cl (mod 16). All M > 0,
    // so fmax/fmed3 ordering == value ordering with first-index tie-break.
    float m1[4][4], m2[4][4];
    #pragma unroll
    for (int rt = 0; rt < 4; ++rt)
      #pragma unroll
      for (int r = 0; r < 4; ++r) { m1[rt][r] = 0.0f; m2[rt][r] = 0.0f; }

    const short8* wb = (const short8*)(Wfrag + (size_t)stage * 131072);
    const float* w2p = W2 + stage * V;   // holds 64 - 0.5*w2

    // ---- ct loop: 64 code-tiles; 2-deep ping-pong B prefetch, no barriers ----
    short8 B0[4], B1[4]; float ca, cb;
    {
      B0[0] = wb[lane]; B0[1] = wb[lane + 64]; B0[2] = wb[lane + 128]; B0[3] = wb[lane + 192];
      ca = w2p[cl];
    }
    #pragma unroll 1
    for (int ct = 0; ct < 64; ct += 2) {
      {   // prefetch ct+1
        int base = (ct + 1) * 256 + lane;
        B1[0] = wb[base]; B1[1] = wb[base + 64]; B1[2] = wb[base + 128]; B1[3] = wb[base + 192];
        cb = w2p[(ct + 1) * 16 + cl];
      }
      {   // compute ct with B0: three parallel 2-deep chains
        int oc = 1023 - (ct * 16 + cl);       // packed low-10 index bits
        f32x4 cv = {ca, ca, ca, ca};          // C1-init: 64 - 0.5*w2
        #pragma unroll
        for (int rt = 0; rt < 4; ++rt) {
          f32x4 C1 = cv, C2 = {0.f,0.f,0.f,0.f}, C3 = {0.f,0.f,0.f,0.f};
          C1 = __builtin_amdgcn_mfma_f32_16x16x32_bf16(Ah[rt][0], B0[0], C1, 0, 0, 0);
          C2 = __builtin_amdgcn_mfma_f32_16x16x32_bf16(Al[rt][0], B0[0], C2, 0, 0, 0);
          C3 = __builtin_amdgcn_mfma_f32_16x16x32_bf16(Ah[rt][0], B0[1], C3, 0, 0, 0);
          C1 = __builtin_amdgcn_mfma_f32_16x16x32_bf16(Ah[rt][1], B0[2], C1, 0, 0, 0);
          C2 = __builtin_amdgcn_mfma_f32_16x16x32_bf16(Al[rt][1], B0[2], C2, 0, 0, 0);
          C3 = __builtin_amdgcn_mfma_f32_16x16x32_bf16(Ah[rt][1], B0[3], C3, 0, 0, 0);
          #pragma unroll
          for (int r = 0; r < 4; ++r) {
            float s = (C1[r] + C2[r]) + C3[r];
            float M = __uint_as_float((__float_as_uint(s) & 0xFFFFFC00u) | (unsigned)oc);
            m2[rt][r] = __builtin_amdgcn_fmed3f(m1[rt][r], M, m2[rt][r]); // new 2nd-max
            m1[rt][r] = fmaxf(m1[rt][r], M);
          }
        }
      }
      {   // prefetch ct+2 (clamped dup at tail: harmless)
        int ctn = (ct + 2 < 64) ? ct + 2 : 63;
        int base = ctn * 256 + lane;
        B0[0] = wb[base]; B0[1] = wb[base + 64]; B0[2] = wb[base + 128]; B0[3] = wb[base + 192];
        ca = w2p[ctn * 16 + cl];
      }
      {   // compute ct+1 with B1
        int oc = 1023 - ((ct + 1) * 16 + cl);
        f32x4 cv = {cb, cb, cb, cb};
        #pragma unroll
        for (int rt = 0; rt < 4; ++rt) {
          f32x4 C1 = cv, C2 = {0.f,0.f,0.f,0.f}, C3 = {0.f,0.f,0.f,0.f};
          C1 = __builtin_amdgcn_mfma_f32_16x16x32_bf16(Ah[rt][0], B1[0], C1, 0, 0, 0);
          C2 = __builtin_amdgcn_mfma_f32_16x16x32_bf16(Al[rt][0], B1[0], C2, 0, 0, 0);
          C3 = __builtin_amdgcn_mfma_f32_16x16x32_bf16(Ah[rt][0], B1[1], C3, 0, 0, 0);
          C1 = __builtin_amdgcn_mfma_f32_16x16x32_bf16(Ah[rt][1], B1[2], C1, 0, 0, 0);
          C2 = __builtin_amdgcn_mfma_f32_16x16x32_bf16(Al[rt][1], B1[2], C2, 0, 0, 0);
          C3 = __builtin_amdgcn_mfma_f32_16x16x32_bf16(Ah[rt][1], B1[3], C3, 0, 0, 0);
          #pragma unroll
          for (int r = 0; r < 4; ++r) {
            float s = (C1[r] + C2[r]) + C3[r];
            float M = __uint_as_float((__float_as_uint(s) & 0xFFFFFC00u) | (unsigned)oc);
            m2[rt][r] = __builtin_amdgcn_fmed3f(m1[rt][r], M, m2[rt][r]);
            m1[rt][r] = fmaxf(m1[rt][r], M);
          }
        }
      }
    } // ct

    // ---- 16-lane butterfly top-2 reduction (plain float max: all M positive) ----
    #pragma unroll
    for (int rt = 0; rt < 4; ++rt)
      #pragma unroll
      for (int r = 0; r < 4; ++r) {
        float a1 = m1[rt][r], a2 = m2[rt][r];
        #pragma unroll
        for (int mask = 1; mask <= 8; mask <<= 1) {
          float o1 = __shfl_xor(a1, mask, 16);
          float o2 = __shfl_xor(a2, mask, 16);
          a2 = fmaxf(fmaxf(a2, o2), fminf(a1, o1));
          a1 = fmaxf(a1, o1);
        }
        if (cl == 0) {
          int row = w * 64 + rt * 16 + q * 4 + r;
          idx_lds[row] = 1023 - (int)(__float_as_uint(a1) & 0x3FFu);
          float gap = a1 - a2;   // bucket-truncated gap; THR covers 2*bucket + split err
          if (gap < TAU_PK) {
            int slot = atomicAdd(&n_rescue, 1);
            rescue_rows[slot] = row;
          }
        }
      }
    __syncthreads();   // idx_lds + rescue flags visible
    int nres = n_rescue;
    __syncthreads();   // all reads of n_rescue done
    if (t == 0) n_rescue = 0;  // for next stage; ordered by the following barriers

    // ---- near-tie rescue: bit-exact numpy-reference emulation ----
    for (int rr_i = 0; rr_i < nres; ++rr_i) {
      int row = rescue_rows[rr_i];
      float p8[8];
      #pragma unroll
      for (int j = 0; j < 8; ++j) p8[j] = __fmul_rn(Rt[row][j], Rt[row][j]);
      #pragma unroll
      for (int i = 1; i < 8; ++i)
        #pragma unroll
        for (int j = 0; j < 8; ++j)
          p8[j] = __fadd_rn(p8[j], __fmul_rn(Rt[row][8 * i + j], Rt[row][8 * i + j]));
      float rrow = __fadd_rn(__fadd_rn(__fadd_rn(p8[0], p8[1]), __fadd_rn(p8[2], p8[3])),
                             __fadd_rn(__fadd_rn(p8[4], p8[5]), __fadd_rn(p8[6], p8[7])));
      const float* eb = emb + (size_t)stage * V * D;
      float bestd = INFINITY; int besti = 0;
      #pragma unroll
      for (int c = 0; c < 4; ++c) {
        int v = t * 4 + c;
        const float* wv = eb + (size_t)v * D;
        float dot = 0.0f;
        #pragma unroll
        for (int d = 0; d < D; ++d) dot = __fmaf_rn(Rt[row][d], wv[d], dot);
        float q8[8];
        #pragma unroll
        for (int j = 0; j < 8; ++j) q8[j] = __fmul_rn(wv[j], wv[j]);
        #pragma unroll
        for (int i = 1; i < 8; ++i)
          #pragma unroll
          for (int j = 0; j < 8; ++j)
            q8[j] = __fadd_rn(q8[j], __fmul_rn(wv[8 * i + j], wv[8 * i + j]));
        float w2e = __fadd_rn(__fadd_rn(__fadd_rn(q8[0], q8[1]), __fadd_rn(q8[2], q8[3])),
                              __fadd_rn(__fadd_rn(q8[4], q8[5]), __fadd_rn(q8[6], q8[7])));
        float d2 = __fadd_rn(__fsub_rn(rrow, __fmul_rn(2.0f, dot)), w2e);
        if (d2 < bestd) { bestd = d2; besti = v; }
      }
      // parallel argmin: packed (ord(d2)<<32 | v) u64 min == min d2, first-index ties
      unsigned long long pk = ((unsigned long long)f2ord(bestd) << 32) | (unsigned int)besti;
      #pragma unroll
      for (int mask = 1; mask <= 32; mask <<= 1) {
        int lo = (int)(unsigned int)pk, hi = (int)(unsigned int)(pk >> 32);
        int olo = __shfl_xor(lo, mask, 64), ohi = __shfl_xor(hi, mask, 64);
        unsigned long long po = ((unsigned long long)(unsigned int)ohi << 32) | (unsigned int)olo;
        pk = po < pk ? po : pk;
      }
      if (lane == 0) resc_pack[w] = pk;
      __syncthreads();
      if (t == 0) {
        unsigned long long b = resc_pack[0];
        if (resc_pack[1] < b) b = resc_pack[1];
        if (resc_pack[2] < b) b = resc_pack[2];
        if (resc_pack[3] < b) b = resc_pack[3];
        idx_lds[row] = (int)(unsigned int)b;
      }
      __syncthreads();
    }

    // ---- update: r -= q (exact fp32); loss += r_new^2 (one thread per row) ----
    {
      int code = idx_lds[t];
      const float4* qp = (const float4*)(emb + (((size_t)stage * V + code) * D));
      #pragma unroll
      for (int k = 0; k < 16; ++k) {
        float4 qv = qp[k];
        float* rp = &Rt[t][k * 4];
        float r0 = rp[0] - qv.x, r1 = rp[1] - qv.y, r2 = rp[2] - qv.z, r3 = rp[3] - qv.w;
        rp[0] = r0; rp[1] = r1; rp[2] = r2; rp[3] = r3;
        loss_acc += r0 * r0 + r1 * r1 + r2 * r2 + r3 * r3;
      }
    }
    // next stage-top __syncthreads() protects Rt reads-after-write
  } // stages

  __syncthreads();

  // ---- epilogue: quantised = latent - r_final (nontemporal dword stores at out+1) ----
  for (int k = 0; k < 64; ++k) {
    int idx = t + k * NT;                  // 0..16383
    int row = idx >> 6, dd = idx & 63;
    float l = latent[row0 * D + idx];
    __builtin_nontemporal_store(l - Rt[row][dd], &out[1 + row0 * D + idx]);
  }

  // ---- loss reduction + atomic ----
  loss_red[t] = loss_acc;
  __syncthreads();
  for (int s = NT / 2; s > 0; s >>= 1) {
    if (t < s) loss_red[t] += loss_red[t + s];
    __syncthreads();
  }
  if (t == 0) atomicAdd(out, loss_red[0] * LOSS_SCALE);
}

extern "C" void kernel_launch(void* const* d_in, const int* in_sizes, int n_in,
                              void* d_out, int out_size, void* d_ws, size_t ws_size,
                              hipStream_t stream) {
  const float* latent = (const float*)d_in[0];
  const float* emb    = (const float*)d_in[1];
  float* out = (float*)d_out;

  unsigned short* Wfrag = (unsigned short*)d_ws;            // HQ*V*D*2 ushorts = 1 MB
  float* W2 = (float*)(Wfrag + (size_t)HQ * V * D * 2);     // HQ*V floats = 16 KB

  vq_prep<<<(HQ * V + NT - 1) / NT, NT, 0, stream>>>(emb, Wfrag, W2, out);
  vq_main<<<M_TOTAL / MR, NT, 0, stream>>>(latent, emb, Wfrag, W2, out);
}

// Round 8
// 521.184 us; speedup vs baseline: 1.4591x; 1.4591x over previous
//
#include <hip/hip_runtime.h>

// Problem constants (fixed by the reference)
#define D        64
#define V        1024
#define HQ       4
#define M_TOTAL  131072      // 32 * 4096 rows
#define MR       256         // rows per block (4 waves x 64 rows/wave)
#define NT       256         // threads per block
#define TAU      4e-3f       // near-tie rescue threshold (bf16-split fast-path err <~6e-4)
#define LOSS_SCALE (1.25f / 8388608.0f)
#define RT_STRIDE 68         // 64 + 4 pad (keeps rows 16B-aligned)

typedef __attribute__((ext_vector_type(8))) short short8;
typedef __attribute__((ext_vector_type(4))) float f32x4;

// ---- ordered-float <-> uint transforms (ascending float == ascending uint) ----
__device__ __forceinline__ unsigned int f2ord(float f) {
  unsigned int b = __float_as_uint(f);
  return b ^ (((unsigned int)((int)b >> 31)) | 0x80000000u);
}
__device__ __forceinline__ float ord2f(unsigned int u) {
  unsigned int b = u ^ ((~((unsigned int)((int)u >> 31))) | 0x80000000u);
  return __uint_as_float(b);
}
// bf16 round-to-nearest-even
__device__ __forceinline__ unsigned short f2bf(float f) {
  unsigned int u = __float_as_uint(f);
  return (unsigned short)((u + 0x7fffu + ((u >> 16) & 1u)) >> 16);
}

// ---- prep: split codebook into bf16 hi/lo in MFMA-fragment order, w2, zero loss ----
// Fragment layout (short8 units within a stage): unit = ((ct*2+kk)*2+hl)*64 + lane,
// holding W[code=ct*16+(lane&15)][k=kk*32+(lane>>4)*8 + j], j=0..7 as bf16.
__global__ void vq_prep(const float* __restrict__ emb, unsigned short* __restrict__ Wfrag,
                        float* __restrict__ W2, float* __restrict__ out) {
  int t = blockIdx.x * NT + threadIdx.x;   // over HQ*V = 4096
  if (t == 0) out[0] = 0.0f;
  if (t >= HQ * V) return;
  int s = t >> 10, v = t & (V - 1);
  int ct = v >> 4, cl = v & 15;
  const float* e = emb + (size_t)t * D;
  float w2 = 0.0f;
  for (int k = 0; k < D; ++k) {
    float f = e[k];
    w2 += f * f;
    unsigned short hb = f2bf(f);
    float fh = __uint_as_float((unsigned int)hb << 16);
    unsigned short lb = f2bf(f - fh);
    int kk = k >> 5, q = (k >> 3) & 3, j = k & 7;
    size_t base = (((size_t)(s * 64 + ct) * 2 + kk) * 2) * 512
                + (size_t)(q * 16 + cl) * 8 + j;
    Wfrag[base]       = hb;   // hl = 0
    Wfrag[base + 512] = lb;   // hl = 1
  }
  W2[t] = w2;
}

// ---- main kernel: 256 rows/block, 4 waves x 64 rows, MFMA bf16-split, B from L2 ----
// R7 (resubmit after infra failure): R0 verbatim (483 us verified; every other
// structure regressed) with ONE change: step-major MFMA issue. Evidence R0/R4/R6:
// MFMA busy-time is constant (~87 us) but wall tracks per-rt chain depth
// (2||4=483, 6-deep=668, 3x2+extra VALU=730) -> the compiler issues rt-groups
// serially, exposing chain-dependency latency per group. Issuing step s of ALL
// 4 rt before step s+1 gives each chain 4-12 intervening MFMA issues (64-192 cyc)
// >= result latency. Per-chain FP accumulation order is bit-identical to R0;
// only cross-chain issue order changes.
__launch_bounds__(NT, 1)
__global__ void vq_main(const float* __restrict__ latent,
                        const float* __restrict__ emb,
                        const unsigned short* __restrict__ Wfrag,
                        const float* __restrict__ W2,
                        float* __restrict__ out) {
  __shared__ float Rt[MR][RT_STRIDE];   // 69.6 KB fp32 residual
  __shared__ int idx_lds[MR];
  __shared__ int n_rescue;
  __shared__ int rescue_rows[MR];
  __shared__ unsigned long long resc_pack[4];   // per-wave rescue winners
  __shared__ float loss_red[NT];

  const int t    = threadIdx.x;
  const int lane = t & 63;
  const int w    = t >> 6;       // wave id: rows [w*64, w*64+64)
  const int cl   = lane & 15;
  const int q    = lane >> 4;
  const size_t row0 = (size_t)blockIdx.x * MR;

  if (t == 0) n_rescue = 0;

  // ---- load latent tile -> Rt (coalesced float4) ----
  {
    const float4* lg = (const float4*)(latent + row0 * D);
    #pragma unroll
    for (int k = 0; k < 16; ++k) {
      int i4 = t + k * NT;                 // 0..4095 float4s
      int row = i4 >> 4, dd = (i4 & 15) * 4;
      *(float4*)&Rt[row][dd] = lg[i4];
    }
  }

  float loss_acc = 0.0f;

  for (int stage = 0; stage < HQ; ++stage) {
    __syncthreads();           // Rt ready (initial load or previous stage's update)

    // ---- build A fragments (bf16 hi/lo) from Rt ----
    short8 Ah[4][2], Al[4][2];
    #pragma unroll
    for (int rt = 0; rt < 4; ++rt)
      #pragma unroll
      for (int kk = 0; kk < 2; ++kk) {
        const float* rp = &Rt[w * 64 + rt * 16 + cl][kk * 32 + q * 8];
        short8 h, l;
        #pragma unroll
        for (int j = 0; j < 8; ++j) {
          float f = rp[j];
          unsigned short hb = f2bf(f);
          float fh = __uint_as_float((unsigned int)hb << 16);
          h[j] = (short)hb;
          l[j] = (short)f2bf(f - fh);
        }
        Ah[rt][kk] = h; Al[rt][kk] = l;
      }

    // per-lane top-2: slot (rt,r) covers row = w*64+rt*16+q*4+r, cols ≡ cl (mod 16)
    float m1[4][4], m2[4][4]; int i1[4][4];
    #pragma unroll
    for (int rt = 0; rt < 4; ++rt)
      #pragma unroll
      for (int r = 0; r < 4; ++r) { m1[rt][r] = INFINITY; m2[rt][r] = INFINITY; i1[rt][r] = 0; }

    const short8* wb = (const short8*)(Wfrag + (size_t)stage * 131072);
    const float* w2p = W2 + stage * V;

    // ---- ct loop: 64 code-tiles; 2-deep ping-pong B prefetch, no barriers ----
    short8 B0[4], B1[4]; float w2a, w2b;
    {
      B0[0] = wb[lane]; B0[1] = wb[lane + 64]; B0[2] = wb[lane + 128]; B0[3] = wb[lane + 192];
      w2a = w2p[cl];
    }
    #pragma unroll 1
    for (int ct = 0; ct < 64; ct += 2) {
      {   // prefetch ct+1
        int base = (ct + 1) * 256 + lane;
        B1[0] = wb[base]; B1[1] = wb[base + 64]; B1[2] = wb[base + 128]; B1[3] = wb[base + 192];
        w2b = w2p[(ct + 1) * 16 + cl];
      }
      {   // compute ct with B0 -- step-major across rt (chain FP order == R0)
        int code = ct * 16 + cl;
        f32x4 C1[4], C2[4];
        #pragma unroll
        for (int rt = 0; rt < 4; ++rt) {
          C1[rt] = (f32x4){0.f,0.f,0.f,0.f};
          C2[rt] = (f32x4){0.f,0.f,0.f,0.f};
        }
        #pragma unroll
        for (int rt = 0; rt < 4; ++rt)
          C1[rt] = __builtin_amdgcn_mfma_f32_16x16x32_bf16(Ah[rt][0], B0[0], C1[rt], 0, 0, 0);
        #pragma unroll
        for (int rt = 0; rt < 4; ++rt)
          C2[rt] = __builtin_amdgcn_mfma_f32_16x16x32_bf16(Al[rt][0], B0[0], C2[rt], 0, 0, 0);
        #pragma unroll
        for (int rt = 0; rt < 4; ++rt)
          C2[rt] = __builtin_amdgcn_mfma_f32_16x16x32_bf16(Al[rt][1], B0[2], C2[rt], 0, 0, 0);
        #pragma unroll
        for (int rt = 0; rt < 4; ++rt)
          C1[rt] = __builtin_amdgcn_mfma_f32_16x16x32_bf16(Ah[rt][1], B0[2], C1[rt], 0, 0, 0);
        #pragma unroll
        for (int rt = 0; rt < 4; ++rt)
          C2[rt] = __builtin_amdgcn_mfma_f32_16x16x32_bf16(Ah[rt][0], B0[1], C2[rt], 0, 0, 0);
        #pragma unroll
        for (int rt = 0; rt < 4; ++rt)
          C2[rt] = __builtin_amdgcn_mfma_f32_16x16x32_bf16(Ah[rt][1], B0[3], C2[rt], 0, 0, 0);
        #pragma unroll
        for (int rt = 0; rt < 4; ++rt)
          #pragma unroll
          for (int r = 0; r < 4; ++r) {
            float s = fmaf(-2.0f, C1[rt][r] + C2[rt][r], w2a);
            m2[rt][r] = __builtin_amdgcn_fmed3f(m1[rt][r], s, m2[rt][r]); // new m2
            bool lt = s < m1[rt][r];
            m1[rt][r] = fminf(m1[rt][r], s);
            i1[rt][r] = lt ? code : i1[rt][r];
          }
      }
      {   // prefetch ct+2 (clamped dup at tail: harmless)
        int ctn = (ct + 2 < 64) ? ct + 2 : 63;
        int base = ctn * 256 + lane;
        B0[0] = wb[base]; B0[1] = wb[base + 64]; B0[2] = wb[base + 128]; B0[3] = wb[base + 192];
        w2a = w2p[ctn * 16 + cl];
      }
      {   // compute ct+1 with B1 -- same step-major order
        int code = (ct + 1) * 16 + cl;
        f32x4 C1[4], C2[4];
        #pragma unroll
        for (int rt = 0; rt < 4; ++rt) {
          C1[rt] = (f32x4){0.f,0.f,0.f,0.f};
          C2[rt] = (f32x4){0.f,0.f,0.f,0.f};
        }
        #pragma unroll
        for (int rt = 0; rt < 4; ++rt)
          C1[rt] = __builtin_amdgcn_mfma_f32_16x16x32_bf16(Ah[rt][0], B1[0], C1[rt], 0, 0, 0);
        #pragma unroll
        for (int rt = 0; rt < 4; ++rt)
          C2[rt] = __builtin_amdgcn_mfma_f32_16x16x32_bf16(Al[rt][0], B1[0], C2[rt], 0, 0, 0);
        #pragma unroll
        for (int rt = 0; rt < 4; ++rt)
          C2[rt] = __builtin_amdgcn_mfma_f32_16x16x32_bf16(Al[rt][1], B1[2], C2[rt], 0, 0, 0);
        #pragma unroll
        for (int rt = 0; rt < 4; ++rt)
          C1[rt] = __builtin_amdgcn_mfma_f32_16x16x32_bf16(Ah[rt][1], B1[2], C1[rt], 0, 0, 0);
        #pragma unroll
        for (int rt = 0; rt < 4; ++rt)
          C2[rt] = __builtin_amdgcn_mfma_f32_16x16x32_bf16(Ah[rt][0], B1[1], C2[rt], 0, 0, 0);
        #pragma unroll
        for (int rt = 0; rt < 4; ++rt)
          C2[rt] = __builtin_amdgcn_mfma_f32_16x16x32_bf16(Ah[rt][1], B1[3], C2[rt], 0, 0, 0);
        #pragma unroll
        for (int rt = 0; rt < 4; ++rt)
          #pragma unroll
          for (int r = 0; r < 4; ++r) {
            float s = fmaf(-2.0f, C1[rt][r] + C2[rt][r], w2b);
            m2[rt][r] = __builtin_amdgcn_fmed3f(m1[rt][r], s, m2[rt][r]);
            bool lt = s < m1[rt][r];
            m1[rt][r] = fminf(m1[rt][r], s);
            i1[rt][r] = lt ? code : i1[rt][r];
          }
      }
    } // ct

    // ---- 16-lane butterfly top-2 reduction ----
    #pragma unroll
    for (int rt = 0; rt < 4; ++rt)
      #pragma unroll
      for (int r = 0; r < 4; ++r) {
        unsigned int phi = f2ord(m1[rt][r]);
        unsigned int plo = (unsigned int)i1[rt][r];
        unsigned int s2  = f2ord(m2[rt][r]);
        #pragma unroll
        for (int mask = 1; mask <= 8; mask <<= 1) {
          unsigned int ohi = (unsigned int)__shfl_xor((int)phi, mask, 16);
          unsigned int olo = (unsigned int)__shfl_xor((int)plo, mask, 16);
          unsigned int os2 = (unsigned int)__shfl_xor((int)s2, mask, 16);
          unsigned long long p  = ((unsigned long long)phi << 32) | plo;
          unsigned long long po = ((unsigned long long)ohi << 32) | olo;
          unsigned int hmax = phi > ohi ? phi : ohi;
          s2 = s2 < os2 ? s2 : os2;
          s2 = s2 < hmax ? s2 : hmax;
          unsigned long long pm = p < po ? p : po;   // ties -> smaller idx (first index)
          phi = (unsigned int)(pm >> 32); plo = (unsigned int)pm;
        }
        if (cl == 0) {
          int row = w * 64 + rt * 16 + q * 4 + r;
          idx_lds[row] = (int)plo;
          float gap = ord2f(s2) - ord2f(phi);
          if (gap < TAU) {
            int slot = atomicAdd(&n_rescue, 1);
            rescue_rows[slot] = row;
          }
        }
      }
    __syncthreads();   // idx_lds + rescue flags visible
    int nres = n_rescue;
    __syncthreads();   // all reads of n_rescue done
    if (t == 0) n_rescue = 0;  // for next stage; ordered by the following barriers

    // ---- near-tie rescue: bit-exact numpy-reference emulation (verified R4/R5) ----
    for (int rr_i = 0; rr_i < nres; ++rr_i) {
      int row = rescue_rows[rr_i];
      float p8[8];
      #pragma unroll
      for (int j = 0; j < 8; ++j) p8[j] = __fmul_rn(Rt[row][j], Rt[row][j]);
      #pragma unroll
      for (int i = 1; i < 8; ++i)
        #pragma unroll
        for (int j = 0; j < 8; ++j)
          p8[j] = __fadd_rn(p8[j], __fmul_rn(Rt[row][8 * i + j], Rt[row][8 * i + j]));
      float rrow = __fadd_rn(__fadd_rn(__fadd_rn(p8[0], p8[1]), __fadd_rn(p8[2], p8[3])),
                             __fadd_rn(__fadd_rn(p8[4], p8[5]), __fadd_rn(p8[6], p8[7])));
      const float* eb = emb + (size_t)stage * V * D;
      float bestd = INFINITY; int besti = 0;
      #pragma unroll
      for (int c = 0; c < 4; ++c) {
        int v = t * 4 + c;
        const float* wv = eb + (size_t)v * D;
        float dot = 0.0f;
        #pragma unroll
        for (int d = 0; d < D; ++d) dot = __fmaf_rn(Rt[row][d], wv[d], dot);
        float q8[8];
        #pragma unroll
        for (int j = 0; j < 8; ++j) q8[j] = __fmul_rn(wv[j], wv[j]);
        #pragma unroll
        for (int i = 1; i < 8; ++i)
          #pragma unroll
          for (int j = 0; j < 8; ++j)
            q8[j] = __fadd_rn(q8[j], __fmul_rn(wv[8 * i + j], wv[8 * i + j]));
        float w2e = __fadd_rn(__fadd_rn(__fadd_rn(q8[0], q8[1]), __fadd_rn(q8[2], q8[3])),
                              __fadd_rn(__fadd_rn(q8[4], q8[5]), __fadd_rn(q8[6], q8[7])));
        float d2 = __fadd_rn(__fsub_rn(rrow, __fmul_rn(2.0f, dot)), w2e);
        if (d2 < bestd) { bestd = d2; besti = v; }
      }
      // parallel argmin: packed (ord(d2)<<32 | v) u64 min == min d2, first-index ties
      unsigned long long pk = ((unsigned long long)f2ord(bestd) << 32) | (unsigned int)besti;
      #pragma unroll
      for (int mask = 1; mask <= 32; mask <<= 1) {
        int lo = (int)(unsigned int)pk, hi = (int)(unsigned int)(pk >> 32);
        int olo = __shfl_xor(lo, mask, 64), ohi = __shfl_xor(hi, mask, 64);
        unsigned long long po = ((unsigned long long)(unsigned int)ohi << 32) | (unsigned int)olo;
        pk = po < pk ? po : pk;
      }
      if (lane == 0) resc_pack[w] = pk;
      __syncthreads();
      if (t == 0) {
        unsigned long long b = resc_pack[0];
        if (resc_pack[1] < b) b = resc_pack[1];
        if (resc_pack[2] < b) b = resc_pack[2];
        if (resc_pack[3] < b) b = resc_pack[3];
        idx_lds[row] = (int)(unsigned int)b;
      }
      __syncthreads();
    }

    // ---- update: r -= q (exact fp32); loss += r_new^2 (one thread per row) ----
    {
      int code = idx_lds[t];
      const float4* qp = (const float4*)(emb + (((size_t)stage * V + code) * D));
      #pragma unroll
      for (int k = 0; k < 16; ++k) {
        float4 qv = qp[k];
        float* rp = &Rt[t][k * 4];
        float r0 = rp[0] - qv.x, r1 = rp[1] - qv.y, r2 = rp[2] - qv.z, r3 = rp[3] - qv.w;
        rp[0] = r0; rp[1] = r1; rp[2] = r2; rp[3] = r3;
        loss_acc += r0 * r0 + r1 * r1 + r2 * r2 + r3 * r3;
      }
    }
    // next stage-top __syncthreads() protects Rt reads-after-write
  } // stages

  __syncthreads();

  // ---- epilogue: quantised = latent - r_final (nontemporal dword stores at out+1) ----
  for (int k = 0; k < 64; ++k) {
    int idx = t + k * NT;                  // 0..16383
    int row = idx >> 6, dd = idx & 63;
    float l = latent[row0 * D + idx];
    __builtin_nontemporal_store(l - Rt[row][dd], &out[1 + row0 * D + idx]);
  }

  // ---- loss reduction + atomic ----
  loss_red[t] = loss_acc;
  __syncthreads();
  for (int s = NT / 2; s > 0; s >>= 1) {
    if (t < s) loss_red[t] += loss_red[t + s];
    __syncthreads();
  }
  if (t == 0) atomicAdd(out, loss_red[0] * LOSS_SCALE);
}

extern "C" void kernel_launch(void* const* d_in, const int* in_sizes, int n_in,
                              void* d_out, int out_size, void* d_ws, size_t ws_size,
                              hipStream_t stream) {
  const float* latent = (const float*)d_in[0];
  const float* emb    = (const float*)d_in[1];
  float* out = (float*)d_out;

  unsigned short* Wfrag = (unsigned short*)d_ws;            // HQ*V*D*2 ushorts = 1 MB
  float* W2 = (float*)(Wfrag + (size_t)HQ * V * D * 2);     // HQ*V floats = 16 KB

  vq_prep<<<(HQ * V + NT - 1) / NT, NT, 0, stream>>>(emb, Wfrag, W2, out);
  vq_main<<<M_TOTAL / MR, NT, 0, stream>>>(latent, emb, Wfrag, W2, out);
}

// Round 9
// 517.901 us; speedup vs baseline: 1.4684x; 1.0063x over previous
//
#include <hip/hip_runtime.h>

// Problem constants (fixed by the reference)
#define D        64
#define V        1024
#define HQ       4
#define M_TOTAL  131072      // 32 * 4096 rows
#define MR       256         // rows per block (4 waves x 64 rows/wave)
#define NT       256         // threads per block
#define TAU      4e-3f       // near-tie rescue threshold (bf16-split fast-path err <~6e-4)
#define LOSS_SCALE (1.25f / 8388608.0f)
#define RT_STRIDE 68         // 64 + 4 pad (keeps rows 16B-aligned)

typedef __attribute__((ext_vector_type(8))) short short8;
typedef __attribute__((ext_vector_type(4))) float f32x4;

// ---- ordered-float <-> uint transforms (ascending float == ascending uint) ----
__device__ __forceinline__ unsigned int f2ord(float f) {
  unsigned int b = __float_as_uint(f);
  return b ^ (((unsigned int)((int)b >> 31)) | 0x80000000u);
}
__device__ __forceinline__ float ord2f(unsigned int u) {
  unsigned int b = u ^ ((~((unsigned int)((int)u >> 31))) | 0x80000000u);
  return __uint_as_float(b);
}
// bf16 round-to-nearest-even
__device__ __forceinline__ unsigned short f2bf(float f) {
  unsigned int u = __float_as_uint(f);
  return (unsigned short)((u + 0x7fffu + ((u >> 16) & 1u)) >> 16);
}

// ---- prep: split codebook into bf16 hi/lo in MFMA-fragment order, w2, zero loss ----
// Fragment layout (short8 units within a stage): unit = ((ct*2+kk)*2+hl)*64 + lane,
// holding W[code=ct*16+(lane&15)][k=kk*32+(lane>>4)*8 + j], j=0..7 as bf16.
__global__ void vq_prep(const float* __restrict__ emb, unsigned short* __restrict__ Wfrag,
                        float* __restrict__ W2, float* __restrict__ out) {
  int t = blockIdx.x * NT + threadIdx.x;   // over HQ*V = 4096
  if (t == 0) out[0] = 0.0f;
  if (t >= HQ * V) return;
  int s = t >> 10, v = t & (V - 1);
  int ct = v >> 4, cl = v & 15;
  const float* e = emb + (size_t)t * D;
  float w2 = 0.0f;
  for (int k = 0; k < D; ++k) {
    float f = e[k];
    w2 += f * f;
    unsigned short hb = f2bf(f);
    float fh = __uint_as_float((unsigned int)hb << 16);
    unsigned short lb = f2bf(f - fh);
    int kk = k >> 5, q = (k >> 3) & 3, j = k & 7;
    size_t base = (((size_t)(s * 64 + ct) * 2 + kk) * 2) * 512
                + (size_t)(q * 16 + cl) * 8 + j;
    Wfrag[base]       = hb;   // hl = 0
    Wfrag[base + 512] = lb;   // hl = 1
  }
  W2[t] = w2;
}

// ---- main kernel: 256 rows/block, 4 waves x 64 rows, MFMA bf16-split, B from L2 ----
// R9: R0 bit-exact, minus dead instructions. Evidence through R8: at 1 wave/SIMD a
// single wave serializes ALL issue (MFMA cannot overlap VALU without a second wave);
// per-ct wall 2250 cyc = issue floor ~1170 + bubbles ~1080. Source order is dead
// (R8 == R0); occupancy routes are dead (R1/R3 spill, R5 -18%). Remaining lever (a):
// cut VALU instruction count. This round: (1) loop-invariant opaque zero f32x4 as
// the C-operand of each chain's first MFMA (D!=C) -- kills the 32 per-ct
// accumulator zero-inits (~64 cyc/ct, ~3%); (2) float4 epilogue loads (~1%).
__launch_bounds__(NT, 1)
__global__ void vq_main(const float* __restrict__ latent,
                        const float* __restrict__ emb,
                        const unsigned short* __restrict__ Wfrag,
                        const float* __restrict__ W2,
                        float* __restrict__ out) {
  __shared__ float Rt[MR][RT_STRIDE];   // 69.6 KB fp32 residual
  __shared__ int idx_lds[MR];
  __shared__ int n_rescue;
  __shared__ int rescue_rows[MR];
  __shared__ unsigned long long resc_pack[4];   // per-wave rescue winners
  __shared__ float loss_red[NT];

  const int t    = threadIdx.x;
  const int lane = t & 63;
  const int w    = t >> 6;       // wave id: rows [w*64, w*64+64)
  const int cl   = lane & 15;
  const int q    = lane >> 4;
  const size_t row0 = (size_t)blockIdx.x * MR;

  if (t == 0) n_rescue = 0;

  // ---- load latent tile -> Rt (coalesced float4) ----
  {
    const float4* lg = (const float4*)(latent + row0 * D);
    #pragma unroll
    for (int k = 0; k < 16; ++k) {
      int i4 = t + k * NT;                 // 0..4095 float4s
      int row = i4 >> 4, dd = (i4 & 15) * 4;
      *(float4*)&Rt[row][dd] = lg[i4];
    }
  }

  float loss_acc = 0.0f;

  // Opaque zero C-operand: compiler can't prove it's 0, so it stays pinned in 4
  // VGPRs across the whole kernel and no per-ct accvgpr zero-inits are emitted.
  // Runtime value IS {0,0,0,0}: 0+x bit-exact (only -0 -> +0, compare-invariant).
  f32x4 Z = {0.f, 0.f, 0.f, 0.f};
  asm volatile("" : "+v"(Z));

  for (int stage = 0; stage < HQ; ++stage) {
    __syncthreads();           // Rt ready (initial load or previous stage's update)

    // ---- build A fragments (bf16 hi/lo) from Rt ----
    short8 Ah[4][2], Al[4][2];
    #pragma unroll
    for (int rt = 0; rt < 4; ++rt)
      #pragma unroll
      for (int kk = 0; kk < 2; ++kk) {
        const float* rp = &Rt[w * 64 + rt * 16 + cl][kk * 32 + q * 8];
        short8 h, l;
        #pragma unroll
        for (int j = 0; j < 8; ++j) {
          float f = rp[j];
          unsigned short hb = f2bf(f);
          float fh = __uint_as_float((unsigned int)hb << 16);
          h[j] = (short)hb;
          l[j] = (short)f2bf(f - fh);
        }
        Ah[rt][kk] = h; Al[rt][kk] = l;
      }

    // per-lane top-2: slot (rt,r) covers row = w*64+rt*16+q*4+r, cols ≡ cl (mod 16)
    float m1[4][4], m2[4][4]; int i1[4][4];
    #pragma unroll
    for (int rt = 0; rt < 4; ++rt)
      #pragma unroll
      for (int r = 0; r < 4; ++r) { m1[rt][r] = INFINITY; m2[rt][r] = INFINITY; i1[rt][r] = 0; }

    const short8* wb = (const short8*)(Wfrag + (size_t)stage * 131072);
    const float* w2p = W2 + stage * V;

    // ---- ct loop: 64 code-tiles; 2-deep ping-pong B prefetch, no barriers ----
    short8 B0[4], B1[4]; float w2a, w2b;
    {
      B0[0] = wb[lane]; B0[1] = wb[lane + 64]; B0[2] = wb[lane + 128]; B0[3] = wb[lane + 192];
      w2a = w2p[cl];
    }
    #pragma unroll 1
    for (int ct = 0; ct < 64; ct += 2) {
      {   // prefetch ct+1
        int base = (ct + 1) * 256 + lane;
        B1[0] = wb[base]; B1[1] = wb[base + 64]; B1[2] = wb[base + 128]; B1[3] = wb[base + 192];
        w2b = w2p[(ct + 1) * 16 + cl];
      }
      {   // compute ct with B0 (chains and FP order identical to R0; first links D!=C from Z)
        int code = ct * 16 + cl;
        #pragma unroll
        for (int rt = 0; rt < 4; ++rt) {
          f32x4 C1 = __builtin_amdgcn_mfma_f32_16x16x32_bf16(Ah[rt][0], B0[0], Z, 0, 0, 0);
          C1 = __builtin_amdgcn_mfma_f32_16x16x32_bf16(Ah[rt][1], B0[2], C1, 0, 0, 0);
          f32x4 C2 = __builtin_amdgcn_mfma_f32_16x16x32_bf16(Al[rt][0], B0[0], Z, 0, 0, 0);
          C2 = __builtin_amdgcn_mfma_f32_16x16x32_bf16(Al[rt][1], B0[2], C2, 0, 0, 0);
          C2 = __builtin_amdgcn_mfma_f32_16x16x32_bf16(Ah[rt][0], B0[1], C2, 0, 0, 0);
          C2 = __builtin_amdgcn_mfma_f32_16x16x32_bf16(Ah[rt][1], B0[3], C2, 0, 0, 0);
          #pragma unroll
          for (int r = 0; r < 4; ++r) {
            float s = fmaf(-2.0f, C1[r] + C2[r], w2a);
            m2[rt][r] = __builtin_amdgcn_fmed3f(m1[rt][r], s, m2[rt][r]); // new m2
            bool lt = s < m1[rt][r];
            m1[rt][r] = fminf(m1[rt][r], s);
            i1[rt][r] = lt ? code : i1[rt][r];
          }
        }
      }
      {   // prefetch ct+2 (clamped dup at tail: harmless)
        int ctn = (ct + 2 < 64) ? ct + 2 : 63;
        int base = ctn * 256 + lane;
        B0[0] = wb[base]; B0[1] = wb[base + 64]; B0[2] = wb[base + 128]; B0[3] = wb[base + 192];
        w2a = w2p[ctn * 16 + cl];
      }
      {   // compute ct+1 with B1
        int code = (ct + 1) * 16 + cl;
        #pragma unroll
        for (int rt = 0; rt < 4; ++rt) {
          f32x4 C1 = __builtin_amdgcn_mfma_f32_16x16x32_bf16(Ah[rt][0], B1[0], Z, 0, 0, 0);
          C1 = __builtin_amdgcn_mfma_f32_16x16x32_bf16(Ah[rt][1], B1[2], C1, 0, 0, 0);
          f32x4 C2 = __builtin_amdgcn_mfma_f32_16x16x32_bf16(Al[rt][0], B1[0], Z, 0, 0, 0);
          C2 = __builtin_amdgcn_mfma_f32_16x16x32_bf16(Al[rt][1], B1[2], C2, 0, 0, 0);
          C2 = __builtin_amdgcn_mfma_f32_16x16x32_bf16(Ah[rt][0], B1[1], C2, 0, 0, 0);
          C2 = __builtin_amdgcn_mfma_f32_16x16x32_bf16(Ah[rt][1], B1[3], C2, 0, 0, 0);
          #pragma unroll
          for (int r = 0; r < 4; ++r) {
            float s = fmaf(-2.0f, C1[r] + C2[r], w2b);
            m2[rt][r] = __builtin_amdgcn_fmed3f(m1[rt][r], s, m2[rt][r]);
            bool lt = s < m1[rt][r];
            m1[rt][r] = fminf(m1[rt][r], s);
            i1[rt][r] = lt ? code : i1[rt][r];
          }
        }
      }
    } // ct

    // ---- 16-lane butterfly top-2 reduction ----
    #pragma unroll
    for (int rt = 0; rt < 4; ++rt)
      #pragma unroll
      for (int r = 0; r < 4; ++r) {
        unsigned int phi = f2ord(m1[rt][r]);
        unsigned int plo = (unsigned int)i1[rt][r];
        unsigned int s2  = f2ord(m2[rt][r]);
        #pragma unroll
        for (int mask = 1; mask <= 8; mask <<= 1) {
          unsigned int ohi = (unsigned int)__shfl_xor((int)phi, mask, 16);
          unsigned int olo = (unsigned int)__shfl_xor((int)plo, mask, 16);
          unsigned int os2 = (unsigned int)__shfl_xor((int)s2, mask, 16);
          unsigned long long p  = ((unsigned long long)phi << 32) | plo;
          unsigned long long po = ((unsigned long long)ohi << 32) | olo;
          unsigned int hmax = phi > ohi ? phi : ohi;
          s2 = s2 < os2 ? s2 : os2;
          s2 = s2 < hmax ? s2 : hmax;
          unsigned long long pm = p < po ? p : po;   // ties -> smaller idx (first index)
          phi = (unsigned int)(pm >> 32); plo = (unsigned int)pm;
        }
        if (cl == 0) {
          int row = w * 64 + rt * 16 + q * 4 + r;
          idx_lds[row] = (int)plo;
          float gap = ord2f(s2) - ord2f(phi);
          if (gap < TAU) {
            int slot = atomicAdd(&n_rescue, 1);
            rescue_rows[slot] = row;
          }
        }
      }
    __syncthreads();   // idx_lds + rescue flags visible
    int nres = n_rescue;
    __syncthreads();   // all reads of n_rescue done
    if (t == 0) n_rescue = 0;  // for next stage; ordered by the following barriers

    // ---- near-tie rescue: bit-exact numpy-reference emulation (verified R4/R5) ----
    for (int rr_i = 0; rr_i < nres; ++rr_i) {
      int row = rescue_rows[rr_i];
      float p8[8];
      #pragma unroll
      for (int j = 0; j < 8; ++j) p8[j] = __fmul_rn(Rt[row][j], Rt[row][j]);
      #pragma unroll
      for (int i = 1; i < 8; ++i)
        #pragma unroll
        for (int j = 0; j < 8; ++j)
          p8[j] = __fadd_rn(p8[j], __fmul_rn(Rt[row][8 * i + j], Rt[row][8 * i + j]));
      float rrow = __fadd_rn(__fadd_rn(__fadd_rn(p8[0], p8[1]), __fadd_rn(p8[2], p8[3])),
                             __fadd_rn(__fadd_rn(p8[4], p8[5]), __fadd_rn(p8[6], p8[7])));
      const float* eb = emb + (size_t)stage * V * D;
      float bestd = INFINITY; int besti = 0;
      #pragma unroll
      for (int c = 0; c < 4; ++c) {
        int v = t * 4 + c;
        const float* wv = eb + (size_t)v * D;
        float dot = 0.0f;
        #pragma unroll
        for (int d = 0; d < D; ++d) dot = __fmaf_rn(Rt[row][d], wv[d], dot);
        float q8[8];
        #pragma unroll
        for (int j = 0; j < 8; ++j) q8[j] = __fmul_rn(wv[j], wv[j]);
        #pragma unroll
        for (int i = 1; i < 8; ++i)
          #pragma unroll
          for (int j = 0; j < 8; ++j)
            q8[j] = __fadd_rn(q8[j], __fmul_rn(wv[8 * i + j], wv[8 * i + j]));
        float w2e = __fadd_rn(__fadd_rn(__fadd_rn(q8[0], q8[1]), __fadd_rn(q8[2], q8[3])),
                              __fadd_rn(__fadd_rn(q8[4], q8[5]), __fadd_rn(q8[6], q8[7])));
        float d2 = __fadd_rn(__fsub_rn(rrow, __fmul_rn(2.0f, dot)), w2e);
        if (d2 < bestd) { bestd = d2; besti = v; }
      }
      // parallel argmin: packed (ord(d2)<<32 | v) u64 min == min d2, first-index ties
      unsigned long long pk = ((unsigned long long)f2ord(bestd) << 32) | (unsigned int)besti;
      #pragma unroll
      for (int mask = 1; mask <= 32; mask <<= 1) {
        int lo = (int)(unsigned int)pk, hi = (int)(unsigned int)(pk >> 32);
        int olo = __shfl_xor(lo, mask, 64), ohi = __shfl_xor(hi, mask, 64);
        unsigned long long po = ((unsigned long long)(unsigned int)ohi << 32) | (unsigned int)olo;
        pk = po < pk ? po : pk;
      }
      if (lane == 0) resc_pack[w] = pk;
      __syncthreads();
      if (t == 0) {
        unsigned long long b = resc_pack[0];
        if (resc_pack[1] < b) b = resc_pack[1];
        if (resc_pack[2] < b) b = resc_pack[2];
        if (resc_pack[3] < b) b = resc_pack[3];
        idx_lds[row] = (int)(unsigned int)b;
      }
      __syncthreads();
    }

    // ---- update: r -= q (exact fp32); loss += r_new^2 (one thread per row) ----
    {
      int code = idx_lds[t];
      const float4* qp = (const float4*)(emb + (((size_t)stage * V + code) * D));
      #pragma unroll
      for (int k = 0; k < 16; ++k) {
        float4 qv = qp[k];
        float* rp = &Rt[t][k * 4];
        float r0 = rp[0] - qv.x, r1 = rp[1] - qv.y, r2 = rp[2] - qv.z, r3 = rp[3] - qv.w;
        rp[0] = r0; rp[1] = r1; rp[2] = r2; rp[3] = r3;
        loss_acc += r0 * r0 + r1 * r1 + r2 * r2 + r3 * r3;
      }
    }
    // next stage-top __syncthreads() protects Rt reads-after-write
  } // stages

  __syncthreads();

  // ---- epilogue: quantised = latent - r_final. float4 loads (latent + Rt);
  // stores stay dword (out+1 is only 4B-aligned) ----
  {
    const float4* lg = (const float4*)(latent + row0 * D);
    for (int k = 0; k < 16; ++k) {
      int i4 = t + k * NT;                 // 0..4095 float4s
      int row = i4 >> 4, dd = (i4 & 15) * 4;
      float4 l4 = lg[i4];
      const float* rp = &Rt[row][dd];
      float o0 = l4.x - rp[0], o1 = l4.y - rp[1], o2 = l4.z - rp[2], o3 = l4.w - rp[3];
      float* op = &out[1 + row0 * D + (size_t)i4 * 4];
      __builtin_nontemporal_store(o0, op);
      __builtin_nontemporal_store(o1, op + 1);
      __builtin_nontemporal_store(o2, op + 2);
      __builtin_nontemporal_store(o3, op + 3);
    }
  }

  // ---- loss reduction + atomic ----
  loss_red[t] = loss_acc;
  __syncthreads();
  for (int s = NT / 2; s > 0; s >>= 1) {
    if (t < s) loss_red[t] += loss_red[t + s];
    __syncthreads();
  }
  if (t == 0) atomicAdd(out, loss_red[0] * LOSS_SCALE);
}

extern "C" void kernel_launch(void* const* d_in, const int* in_sizes, int n_in,
                              void* d_out, int out_size, void* d_ws, size_t ws_size,
                              hipStream_t stream) {
  const float* latent = (const float*)d_in[0];
  const float* emb    = (const float*)d_in[1];
  float* out = (float*)d_out;

  unsigned short* Wfrag = (unsigned short*)d_ws;            // HQ*V*D*2 ushorts = 1 MB
  float* W2 = (float*)(Wfrag + (size_t)HQ * V * D * 2);     // HQ*V floats = 16 KB

  vq_prep<<<(HQ * V + NT - 1) / NT, NT, 0, stream>>>(emb, Wfrag, W2, out);
  vq_main<<<M_TOTAL / MR, NT, 0, stream>>>(latent, emb, Wfrag, W2, out);
}